// Round 3
// baseline (969.421 us; speedup 1.0000x reference)
//
#include <hip/hip_runtime.h>

#define BB 2
#define NN 384
#define FF 64
#define HH 128
#define EE 4
#define ETILE 64
#define NCHUNK (NN / ETILE)   // 6

using f4 = float4;

__device__ __forceinline__ float fast_tanh(float x) {
    float e = __expf(2.0f * x);
    return 1.0f - 2.0f / (e + 1.0f);
}
__device__ __forceinline__ float fast_sigmoid(float x) {
    return 1.0f / (1.0f + __expf(-x));
}

// ---------------- Kernel A: S/T precompute --------------------------------
// S[b,n,o] = (h[b,n]*mask) @ We1[0:64]         (source rows)
// T[b,n,o] = (h[b,n]*mask) @ We1[64:128] + be1 (target rows, bias folded)
__global__ __launch_bounds__(128) void pre_kernel(
    const float* __restrict__ h, const float* __restrict__ mask,
    const float* __restrict__ We1, const float* __restrict__ be1,
    float* __restrict__ Sg, float* __restrict__ Tg)
{
    const int bn = blockIdx.x;
    const int t  = threadIdx.x;
    __shared__ float hl[FF];
    const float mk = mask[bn];
    if (t < FF) hl[t] = h[bn * FF + t] * mk;
    __syncthreads();
    float s = 0.f, tv = be1[t];
#pragma unroll 8
    for (int f = 0; f < FF; ++f) {
        const float hv = hl[f];
        s  = fmaf(hv, We1[f * HH + t], s);
        tv = fmaf(hv, We1[(FF + f) * HH + t], tv);
    }
    Sg[bn * HH + t] = s;
    Tg[bn * HH + t] = tv;
}

// ---------------- Edge kernel ---------------------------------------------
// one block = (b, i, 64-edge j chunk). 256 threads.
// GEMM mapping: thread t -> edge e = t&63, output slice o0 = (t>>6)*32.
// o0 is wave-uniform (readfirstlane) => weight reads are uniform loads the
// backend promotes to s_load (SGPR operand in v_fma); A-operand is one
// conflict-free ds_read_b32 per k. LDS pipe ~12% of VALU wall.
// unroll 2 (not 4): keeps <=64 weight floats in SGPR flight so RA never
// breaks uniform-load promotion on SGPR pressure.
__device__ __forceinline__ void gemm_stage_s(
    const float* __restrict__ Wg,   // [128][128] global weights (row-major)
    const float* __restrict__ mTb,  // LDS [128][64]  (k-major, m1 or m)
    float acc[32], const int e, const int o0)
{
#pragma unroll 2
    for (int kk = 0; kk < HH; ++kk) {
        const float a = mTb[kk * ETILE + e];
        const float* wr = &Wg[kk * HH + o0];   // wave-uniform address
#pragma unroll
        for (int q = 0; q < 8; ++q) {
            const f4 w = *(const f4*)&wr[q * 4];
            acc[q * 4 + 0] = fmaf(a, w.x, acc[q * 4 + 0]);
            acc[q * 4 + 1] = fmaf(a, w.y, acc[q * 4 + 1]);
            acc[q * 4 + 2] = fmaf(a, w.z, acc[q * 4 + 2]);
            acc[q * 4 + 3] = fmaf(a, w.w, acc[q * 4 + 3]);
        }
    }
}

__global__ __launch_bounds__(256, 4) void edge_kernel(
    const float* __restrict__ coord, const float* __restrict__ edge_attr,
    const float* __restrict__ mask,  const float* __restrict__ We1,
    const float* __restrict__ We2,   const float* __restrict__ be2,
    const float* __restrict__ Wa1,   const float* __restrict__ ba1,
    const float* __restrict__ Wa2,   const float* __restrict__ ba2,
    const float* __restrict__ Wc1,   const float* __restrict__ bc1,
    const float* __restrict__ Wc2,
    const float* __restrict__ Sg,    const float* __restrict__ Tg,
    float* __restrict__ ef_out,
    float* __restrict__ agg_part,    // [B*N*NCHUNK][128]
    float* __restrict__ cag_part)    // [B*N*NCHUNK][3]
{
    __shared__ float mT[HH * ETILE];   // [o/k][e]  m1, then m in place (32 KB)
    __shared__ float Tb[HH];
    __shared__ float sd_l[ETILE];
    __shared__ float cd_l[ETILE][3];
    __shared__ float ea_l[ETILE][4];
    __shared__ float attn_l[ETILE];
    __shared__ float embed_l[ETILE];
    __shared__ float part[256];

    const int bid = blockIdx.x;
    const int jc  = bid % NCHUNK;
    const int i   = (bid / NCHUNK) % NN;
    const int b   = bid / (NCHUNK * NN);
    const int j0  = jc * ETILE;
    const int t   = threadIdx.x;
    const int e   = t & 63;
    const int wv  = __builtin_amdgcn_readfirstlane(t >> 6);  // wave id, SGPR
    const int o0  = wv * 32;

    if (t < HH) Tb[t] = Tg[(b * NN + i) * HH + t];
    if (t < ETILE) {
        const int j = j0 + t;
        const float mi = mask[b * NN + i], mj = mask[b * NN + j];
        const float m2 = mi * mj;
        const float d0 = coord[(b * NN + i) * 3 + 0] * mi - coord[(b * NN + j) * 3 + 0] * mj;
        const float d1 = coord[(b * NN + i) * 3 + 1] * mi - coord[(b * NN + j) * 3 + 1] * mj;
        const float d2 = coord[(b * NN + i) * 3 + 2] * mi - coord[(b * NN + j) * 3 + 2] * mj;
        sd_l[t] = (d0 * d0 + d1 * d1 + d2 * d2) * m2;
        cd_l[t][0] = d0 * m2; cd_l[t][1] = d1 * m2; cd_l[t][2] = d2 * m2;
        const f4 ea = *(const f4*)&edge_attr[(((size_t)b * NN + i) * NN + j) * EE];
        ea_l[t][0] = ea.x; ea_l[t][1] = ea.y; ea_l[t][2] = ea.z; ea_l[t][3] = ea.w;
    }
    __syncthreads();                                          // B1

    // ---- phase 0: m1 = tanh(S[j] + T[i] + radial*W1r + ea@W1e) ----
    {
        const float rad = sd_l[e];
        const float ea0 = ea_l[e][0], ea1 = ea_l[e][1], ea2 = ea_l[e][2], ea3 = ea_l[e][3];
        const float* Srow = &Sg[((size_t)b * NN + (j0 + e)) * HH];
#pragma unroll
        for (int s = 0; s < 8; ++s) {
            const int o = o0 + s * 4;                         // wave-uniform
            const f4 sv = *(const f4*)&Srow[o];
            const f4 tb = *(const f4*)&Tb[o];
            const f4 wr = *(const f4*)&We1[128 * HH + o];
            const f4 w0 = *(const f4*)&We1[129 * HH + o];
            const f4 w1 = *(const f4*)&We1[130 * HH + o];
            const f4 w2 = *(const f4*)&We1[131 * HH + o];
            const f4 w3 = *(const f4*)&We1[132 * HH + o];
            float p;
            p = sv.x + tb.x + rad * wr.x + ea0 * w0.x + ea1 * w1.x + ea2 * w2.x + ea3 * w3.x;
            mT[(o + 0) * ETILE + e] = fast_tanh(p);
            p = sv.y + tb.y + rad * wr.y + ea0 * w0.y + ea1 * w1.y + ea2 * w2.y + ea3 * w3.y;
            mT[(o + 1) * ETILE + e] = fast_tanh(p);
            p = sv.z + tb.z + rad * wr.z + ea0 * w0.z + ea1 * w1.z + ea2 * w2.z + ea3 * w3.z;
            mT[(o + 2) * ETILE + e] = fast_tanh(p);
            p = sv.w + tb.w + rad * wr.w + ea0 * w0.w + ea1 * w1.w + ea2 * w2.w + ea3 * w3.w;
            mT[(o + 3) * ETILE + e] = fast_tanh(p);
        }
    }
    __syncthreads();                                          // B2

    float acc[32];

    // ---- stage 1: m = tanh(m1 @ We2 + be2), in-place into mT ----
#pragma unroll
    for (int q = 0; q < 32; ++q) acc[q] = 0.f;
    gemm_stage_s(We2, mT, acc, e, o0);
    __syncthreads();                                          // B3 (all reads of m1 done)
#pragma unroll
    for (int q = 0; q < 32; ++q)
        mT[(o0 + q) * ETILE + e] = fast_tanh(acc[q] + be2[o0 + q]);
    __syncthreads();                                          // B4

    // ---- stage 2: attn = sigmoid( sum_o tanh(m@Wa1+ba1)[o]*Wa2[o] + ba2 ) ----
#pragma unroll
    for (int q = 0; q < 32; ++q) acc[q] = 0.f;
    gemm_stage_s(Wa1, mT, acc, e, o0);
    {
        float pv = 0.f;
#pragma unroll
        for (int q = 0; q < 32; ++q)
            pv += fast_tanh(acc[q] + ba1[o0 + q]) * Wa2[o0 + q];
        part[wv * 64 + e] = pv;
    }
    __syncthreads();                                          // B5
    if (t < ETILE)
        attn_l[t] = fast_sigmoid(part[t] + part[64 + t] + part[128 + t] +
                                 part[192 + t] + ba2[0]);
    __syncthreads();                                          // B6

    // ---- stage 3: embed = sum_o tanh(attn*(m@Wc1)+bc1)[o] * Wc2[o] ----
#pragma unroll
    for (int q = 0; q < 32; ++q) acc[q] = 0.f;
    gemm_stage_s(Wc1, mT, acc, e, o0);
    {
        const float at = attn_l[e];
        float pv = 0.f;
#pragma unroll
        for (int q = 0; q < 32; ++q)
            pv += fast_tanh(at * acc[q] + bc1[o0 + q]) * Wc2[o0 + q];
        part[wv * 64 + e] = pv;
    }
    __syncthreads();                                          // B7
    if (t < ETILE)
        embed_l[t] = part[t] + part[64 + t] + part[128 + t] + part[192 + t];
    __syncthreads();                                          // B8

    // ---- epilogue A: edge_feat = m*attn (thread: edge e, outputs o0..o0+31) ----
    {
        const float at = attn_l[e];
        float* orow = &ef_out[(((size_t)b * NN + i) * NN + (j0 + e)) * HH + o0];
#pragma unroll
        for (int s = 0; s < 8; ++s) {
            f4 v;
            v.x = mT[(o0 + s * 4 + 0) * ETILE + e] * at;
            v.y = mT[(o0 + s * 4 + 1) * ETILE + e] * at;
            v.z = mT[(o0 + s * 4 + 2) * ETILE + e] * at;
            v.w = mT[(o0 + s * 4 + 3) * ETILE + e] * at;
            *(f4*)&orow[s * 4] = v;
        }
    }

    // ---- epilogue B: agg[o] = sum_e m[e][o]*attn[e] (bank-staggered dot) ----
    {
        const int o = t >> 1, hb = (t & 1) * 32;
        float pa = 0.f;
#pragma unroll 8
        for (int s2 = 0; s2 < 32; ++s2) {
            const int ee = hb + ((o + s2) & 31);
            pa = fmaf(mT[o * ETILE + ee], attn_l[ee], pa);
        }
        part[t] = pa;
    }

    // ---- epilogue C: coord aggregation (wave 0) ----
    if (t < ETILE) {
        const float em = embed_l[t];
        float tr0 = cd_l[t][0] * em, tr1 = cd_l[t][1] * em, tr2 = cd_l[t][2] * em;
#pragma unroll
        for (int off = 1; off < 64; off <<= 1) {
            tr0 += __shfl_xor(tr0, off);
            tr1 += __shfl_xor(tr1, off);
            tr2 += __shfl_xor(tr2, off);
        }
        if (t == 0) {
            cag_part[(size_t)bid * 3 + 0] = tr0;
            cag_part[(size_t)bid * 3 + 1] = tr1;
            cag_part[(size_t)bid * 3 + 2] = tr2;
        }
    }
    __syncthreads();                                          // B9
    if (t < HH)
        agg_part[(size_t)bid * HH + t] = part[2 * t] + part[2 * t + 1];
}

// ---------------- Node kernel ---------------------------------------------
__global__ __launch_bounds__(128) void node_kernel(
    const float* __restrict__ h, const float* __restrict__ coord,
    const float* __restrict__ node_attr, const float* __restrict__ mask,
    const float* __restrict__ Wn1, const float* __restrict__ bn1,
    const float* __restrict__ Wn2, const float* __restrict__ bn2,
    const float* __restrict__ agg_part, const float* __restrict__ cag_part,
    float* __restrict__ h_out, float* __restrict__ c_out)
{
    const int bn = blockIdx.x;   // b*N + i
    const int b  = bn / NN;
    const int t  = threadIdx.x;
    __shared__ float nl[2 * FF + HH];
    __shared__ float ul[HH];
    __shared__ float msp[2];
    const float mi = mask[bn];

    float s = mask[b * NN + t] + mask[b * NN + t + 128] + mask[b * NN + t + 256];
#pragma unroll
    for (int off = 1; off < 64; off <<= 1) s += __shfl_xor(s, off);
    if ((t & 63) == 0) msp[t >> 6] = s;

    if (t < FF) nl[t] = h[bn * FF + t] * mi;
    else        nl[t] = node_attr[bn * FF + (t - FF)] * mi;
    {
        float a = 0.f;
#pragma unroll
        for (int jc = 0; jc < NCHUNK; ++jc)
            a += agg_part[((size_t)bn * NCHUNK + jc) * HH + t];
        nl[2 * FF + t] = a * mi;
    }
    __syncthreads();

    float acc = bn1[t];
#pragma unroll 8
    for (int k = 0; k < 2 * FF + HH; ++k)
        acc = fmaf(nl[k], Wn1[k * HH + t], acc);
    ul[t] = fast_tanh(acc);
    __syncthreads();

    if (t < FF) {
        float a = bn2[t];
#pragma unroll 8
        for (int o = 0; o < HH; ++o)
            a = fmaf(ul[o], Wn2[o * FF + t], a);
        h_out[bn * FF + t] = (h[bn * FF + t] * mi + a) * mi;
    } else if (t < FF + 3) {
        const int d = t - FF;
        float cag = 0.f;
        for (int jc = 0; jc < NCHUNK; ++jc)
            cag += cag_part[((size_t)bn * NCHUNK + jc) * 3 + d];
        const float msum  = msp[0] + msp[1];
        const float denom = mi * msum + 1e-10f;
        c_out[bn * 3 + d] = (coord[bn * 3 + d] * mi + cag / denom) * mi;
    }
}

// ---------------- launch ---------------------------------------------------
extern "C" void kernel_launch(void* const* d_in, const int* in_sizes, int n_in,
                              void* d_out, int out_size, void* d_ws, size_t ws_size,
                              hipStream_t stream)
{
    const float* h         = (const float*)d_in[0];
    const float* coord     = (const float*)d_in[1];
    const float* edge_attr = (const float*)d_in[2];
    const float* node_attr = (const float*)d_in[3];
    const float* mask      = (const float*)d_in[4];
    const float* We1 = (const float*)d_in[5];
    const float* be1 = (const float*)d_in[6];
    const float* We2 = (const float*)d_in[7];
    const float* be2 = (const float*)d_in[8];
    const float* Wa1 = (const float*)d_in[9];
    const float* ba1 = (const float*)d_in[10];
    const float* Wa2 = (const float*)d_in[11];
    const float* ba2 = (const float*)d_in[12];
    const float* Wn1 = (const float*)d_in[13];
    const float* bn1 = (const float*)d_in[14];
    const float* Wn2 = (const float*)d_in[15];
    const float* bn2 = (const float*)d_in[16];
    const float* Wc1 = (const float*)d_in[17];
    const float* bc1 = (const float*)d_in[18];
    const float* Wc2 = (const float*)d_in[19];

    float* out    = (float*)d_out;
    float* h_out  = out;
    float* c_out  = out + (size_t)BB * NN * FF;
    float* ef_out = c_out + (size_t)BB * NN * 3;

    float* ws = (float*)d_ws;
    float* Sg = ws;                                             // B*N*128
    float* Tg = Sg + (size_t)BB * NN * HH;                      // B*N*128
    float* agg_part = Tg + (size_t)BB * NN * HH;                // B*N*6*128
    float* cag_part = agg_part + (size_t)BB * NN * NCHUNK * HH; // B*N*6*3

    pre_kernel<<<BB * NN, 128, 0, stream>>>(h, mask, We1, be1, Sg, Tg);
    edge_kernel<<<BB * NN * NCHUNK, 256, 0, stream>>>(
        coord, edge_attr, mask, We1, We2, be2, Wa1, ba1, Wa2, ba2,
        Wc1, bc1, Wc2, Sg, Tg, ef_out, agg_part, cag_part);
    node_kernel<<<BB * NN, 128, 0, stream>>>(
        h, coord, node_attr, mask, Wn1, bn1, Wn2, bn2,
        agg_part, cag_part, h_out, c_out);
}

// Round 6
// 488.365 us; speedup vs baseline: 1.9850x; 1.9850x over previous
//
#include <hip/hip_runtime.h>

#define BB 2
#define NN 384
#define FF 64
#define HH 128
#define EE 4
#define ETILE 64
#define NCHUNK (NN / ETILE)   // 6

using f4 = float4;
typedef __attribute__((ext_vector_type(8))) short          bf16x8;
typedef __attribute__((ext_vector_type(8))) unsigned short u16x8;
typedef __attribute__((ext_vector_type(4))) unsigned int   u32x4;
typedef __attribute__((ext_vector_type(4))) float          f32x4;

__device__ __forceinline__ float fast_tanh(float x) {
    float e = __expf(2.0f * x);
    return 1.0f - 2.0f / (e + 1.0f);
}
__device__ __forceinline__ float fast_sigmoid(float x) {
    return 1.0f / (1.0f + __expf(-x));
}
__device__ __forceinline__ unsigned short f2bf(float x) {   // RNE
    unsigned int u = __float_as_uint(x);
    unsigned int r = (u + 0x7fffu + ((u >> 16) & 1u)) >> 16;
    return (unsigned short)r;
}
__device__ __forceinline__ float bf2f(unsigned short h) {
    return __uint_as_float(((unsigned int)h) << 16);
}
__device__ __forceinline__ bf16x8 as_bf16x8(u32x4 v) {
    union { u32x4 u; bf16x8 b; } c; c.u = v; return c.b;
}

// ---------------- Kernel A: S/T precompute (fp32) --------------------------
__global__ __launch_bounds__(128) void pre_kernel(
    const float* __restrict__ h, const float* __restrict__ mask,
    const float* __restrict__ We1, const float* __restrict__ be1,
    float* __restrict__ Sg, float* __restrict__ Tg)
{
    const int bn = blockIdx.x;
    const int t  = threadIdx.x;
    __shared__ float hl[FF];
    const float mk = mask[bn];
    if (t < FF) hl[t] = h[bn * FF + t] * mk;
    __syncthreads();
    float s = 0.f, tv = be1[t];
#pragma unroll 8
    for (int f = 0; f < FF; ++f) {
        const float hv = hl[f];
        s  = fmaf(hv, We1[f * HH + t], s);
        tv = fmaf(hv, We1[(FF + f) * HH + t], tv);
    }
    Sg[bn * HH + t] = s;
    Tg[bn * HH + t] = tv;
}

// ---------------- Kernel B: weight transpose + bf16 hi/lo split ------------
// WT[mat][sel][col][k]  (bf16, row-major in k) — B-fragment friendly.
__global__ __launch_bounds__(128) void wconv_kernel(
    const float* __restrict__ W0, const float* __restrict__ W1,
    const float* __restrict__ W2, unsigned short* __restrict__ WT)
{
    const int mat = blockIdx.x >> 7;
    const int o   = blockIdx.x & 127;
    const int k   = threadIdx.x;
    const float* src = (mat == 0) ? W0 : (mat == 1) ? W1 : W2;
    const float w = src[k * HH + o];
    const unsigned short hi = f2bf(w);
    const unsigned short lo = f2bf(w - bf2f(hi));
    WT[(mat * 2 + 0) * 16384 + o * HH + k] = hi;
    WT[(mat * 2 + 1) * 16384 + o * HH + k] = lo;
}

// ---------------- MFMA pass helpers ----------------------------------------
// A-tile LDS layout: ushort A[64][128], 16B chunks XOR-swizzled:
//   element (row,col) lives at row*128 + ((col>>3) ^ (row&15))*8 + (col&7)
// A-fragment (16x16x32): lane reads row 16rt+l15, k = kb*32 + l4*8 .. +7
//   -> chunk kb*4+l4, phys = (kb*4+l4)^l15 -> one aligned b128.
__device__ __forceinline__ void mfma_pass_dual(
    const ushort* __restrict__ A1, const ushort* __restrict__ A2,
    const ushort* __restrict__ WTp, f32x4 acc[4][2],
    const int l15, const int l4, const int c0)
{
    u32x4 Bf[2][4];
#pragma unroll
    for (int ct = 0; ct < 2; ++ct)
#pragma unroll
        for (int kb = 0; kb < 4; ++kb)
            Bf[ct][kb] = *(const u32x4*)&WTp[(c0 + ct * 16 + l15) * HH + kb * 32 + l4 * 8];
#pragma unroll
    for (int rt = 0; rt < 4; ++rt) {
        bf16x8 Af1[4], Af2[4];
#pragma unroll
        for (int kb = 0; kb < 4; ++kb) {
            const int idx = (16 * rt + l15) * HH + (((kb * 4 + l4) ^ l15) * 8);
            Af1[kb] = *(const bf16x8*)&A1[idx];
            Af2[kb] = *(const bf16x8*)&A2[idx];
        }
#pragma unroll
        for (int ct = 0; ct < 2; ++ct)
#pragma unroll
            for (int kb = 0; kb < 4; ++kb)
                acc[rt][ct] = __builtin_amdgcn_mfma_f32_16x16x32_bf16(
                    Af1[kb], as_bf16x8(Bf[ct][kb]), acc[rt][ct], 0, 0, 0);
#pragma unroll
        for (int ct = 0; ct < 2; ++ct)
#pragma unroll
            for (int kb = 0; kb < 4; ++kb)
                acc[rt][ct] = __builtin_amdgcn_mfma_f32_16x16x32_bf16(
                    Af2[kb], as_bf16x8(Bf[ct][kb]), acc[rt][ct], 0, 0, 0);
    }
}

__device__ __forceinline__ void mfma_pass_single(
    const ushort* __restrict__ A1, const ushort* __restrict__ WTp,
    f32x4 acc[4][2], const int l15, const int l4, const int c0)
{
    u32x4 Bf[2][4];
#pragma unroll
    for (int ct = 0; ct < 2; ++ct)
#pragma unroll
        for (int kb = 0; kb < 4; ++kb)
            Bf[ct][kb] = *(const u32x4*)&WTp[(c0 + ct * 16 + l15) * HH + kb * 32 + l4 * 8];
#pragma unroll
    for (int rt = 0; rt < 4; ++rt) {
        bf16x8 Af1[4];
#pragma unroll
        for (int kb = 0; kb < 4; ++kb) {
            const int idx = (16 * rt + l15) * HH + (((kb * 4 + l4) ^ l15) * 8);
            Af1[kb] = *(const bf16x8*)&A1[idx];
        }
#pragma unroll
        for (int ct = 0; ct < 2; ++ct)
#pragma unroll
            for (int kb = 0; kb < 4; ++kb)
                acc[rt][ct] = __builtin_amdgcn_mfma_f32_16x16x32_bf16(
                    Af1[kb], as_bf16x8(Bf[ct][kb]), acc[rt][ct], 0, 0, 0);
    }
}

// ---------------- Edge kernel (MFMA bf16x3) --------------------------------
__global__ __launch_bounds__(256, 4) void edge_kernel(
    const float* __restrict__ coord, const float* __restrict__ edge_attr,
    const float* __restrict__ mask,  const float* __restrict__ We1,
    const float* __restrict__ be2,   const float* __restrict__ ba1,
    const float* __restrict__ Wa2,   const float* __restrict__ ba2,
    const float* __restrict__ bc1,   const float* __restrict__ Wc2,
    const float* __restrict__ Sg,    const float* __restrict__ Tg,
    const unsigned short* __restrict__ WT,
    float* __restrict__ ef_out,
    float* __restrict__ agg_part,    // [B*N*NCHUNK][128]
    float* __restrict__ cag_part)    // [B*N*NCHUNK][3]
{
    __shared__ ushort Ah[ETILE * HH];   // 16 KB, swizzled bf16 hi
    __shared__ ushort Al[ETILE * HH];   // 16 KB, swizzled bf16 lo
    __shared__ float Tb[HH];
    __shared__ float sd_l[ETILE];
    __shared__ float cd_l[ETILE][3];
    __shared__ float ea_l[ETILE][4];
    __shared__ float attn_l[ETILE];
    __shared__ float embed_l[ETILE];
    __shared__ float part[4 * ETILE];

    const int bid = blockIdx.x;
    const int jc  = bid % NCHUNK;
    const int i   = (bid / NCHUNK) % NN;
    const int b   = bid / (NCHUNK * NN);
    const int j0  = jc * ETILE;
    const int t   = threadIdx.x;
    const int e   = t & 63;                                   // lane id too
    const int wv  = __builtin_amdgcn_readfirstlane(t >> 6);   // wave id
    const int l15 = e & 15, l4 = e >> 4;
    const int c0  = wv * 32;                                  // wave col base

    const unsigned short* We2h = WT;
    const unsigned short* We2l = WT + 16384;
    const unsigned short* Wa1h = WT + 32768;
    const unsigned short* Wa1l = WT + 49152;
    const unsigned short* Wc1h = WT + 65536;

    // per-lane column constants (cols c0+l15 and c0+16+l15)
    const float be2a = be2[c0 + l15],      be2b = be2[c0 + 16 + l15];
    const float ba1a = ba1[c0 + l15],      ba1b = ba1[c0 + 16 + l15];
    const float wa2a = Wa2[c0 + l15],      wa2b = Wa2[c0 + 16 + l15];
    const float bc1a = bc1[c0 + l15],      bc1b = bc1[c0 + 16 + l15];
    const float wc2a = Wc2[c0 + l15],      wc2b = Wc2[c0 + 16 + l15];
    const float ba2s = ba2[0];

    if (t < HH) Tb[t] = Tg[(b * NN + i) * HH + t];
    if (t < ETILE) {
        const int j = j0 + t;
        const float mi = mask[b * NN + i], mj = mask[b * NN + j];
        const float m2 = mi * mj;
        const float d0 = coord[(b * NN + i) * 3 + 0] * mi - coord[(b * NN + j) * 3 + 0] * mj;
        const float d1 = coord[(b * NN + i) * 3 + 1] * mi - coord[(b * NN + j) * 3 + 1] * mj;
        const float d2 = coord[(b * NN + i) * 3 + 2] * mi - coord[(b * NN + j) * 3 + 2] * mj;
        sd_l[t] = (d0 * d0 + d1 * d1 + d2 * d2) * m2;
        cd_l[t][0] = d0 * m2; cd_l[t][1] = d1 * m2; cd_l[t][2] = d2 * m2;
        const f4 ea = *(const f4*)&edge_attr[(((size_t)b * NN + i) * NN + j) * EE];
        ea_l[t][0] = ea.x; ea_l[t][1] = ea.y; ea_l[t][2] = ea.z; ea_l[t][3] = ea.w;
    }
    __syncthreads();                                          // B1

    // ---- phase 0: m1 = tanh(S[j] + T[i] + rad*W1r + ea@W1e) -> Ah/Al ----
    {
        const float rad = sd_l[e];
        const float ea0 = ea_l[e][0], ea1 = ea_l[e][1], ea2 = ea_l[e][2], ea3 = ea_l[e][3];
        const float* Srow = &Sg[((size_t)b * NN + (j0 + e)) * HH];
#pragma unroll
        for (int s = 0; s < 4; ++s) {                         // 4 chunks of 8
            u16x8 hp, lp;
#pragma unroll
            for (int hq = 0; hq < 2; ++hq) {
                const int o = c0 + s * 8 + hq * 4;
                const f4 sv = *(const f4*)&Srow[o];
                const f4 tb = *(const f4*)&Tb[o];
                const f4 wr = *(const f4*)&We1[128 * HH + o];
                const f4 w0 = *(const f4*)&We1[129 * HH + o];
                const f4 w1 = *(const f4*)&We1[130 * HH + o];
                const f4 w2 = *(const f4*)&We1[131 * HH + o];
                const f4 w3 = *(const f4*)&We1[132 * HH + o];
                float pv[4];
                pv[0] = sv.x + tb.x + rad * wr.x + ea0 * w0.x + ea1 * w1.x + ea2 * w2.x + ea3 * w3.x;
                pv[1] = sv.y + tb.y + rad * wr.y + ea0 * w0.y + ea1 * w1.y + ea2 * w2.y + ea3 * w3.y;
                pv[2] = sv.z + tb.z + rad * wr.z + ea0 * w0.z + ea1 * w1.z + ea2 * w2.z + ea3 * w3.z;
                pv[3] = sv.w + tb.w + rad * wr.w + ea0 * w0.w + ea1 * w1.w + ea2 * w2.w + ea3 * w3.w;
#pragma unroll
                for (int q = 0; q < 4; ++q) {
                    const float v = fast_tanh(pv[q]);
                    const unsigned short hv = f2bf(v);
                    hp[hq * 4 + q] = hv;
                    lp[hq * 4 + q] = f2bf(v - bf2f(hv));
                }
            }
            const int phys = (wv * 4 + s) ^ (e & 15);
            *(u16x8*)&Ah[e * HH + phys * 8] = hp;
            *(u16x8*)&Al[e * HH + phys * 8] = lp;
        }
    }
    __syncthreads();                                          // B2

    f32x4 acc[4][2];

    // ---- stage 1: m = tanh(m1 @ We2 + be2) (bf16x3), in place ----
#pragma unroll
    for (int rt = 0; rt < 4; ++rt)
#pragma unroll
        for (int ct = 0; ct < 2; ++ct) acc[rt][ct] = (f32x4){0.f, 0.f, 0.f, 0.f};
    mfma_pass_dual(Ah, Al, We2h, acc, l15, l4, c0);   // hi*Whi + lo*Whi
    mfma_pass_single(Ah, We2l, acc, l15, l4, c0);     // hi*Wlo
    __syncthreads();                                          // B3 (m1 reads done)
#pragma unroll
    for (int rt = 0; rt < 4; ++rt)
#pragma unroll
        for (int ct = 0; ct < 2; ++ct)
#pragma unroll
            for (int r = 0; r < 4; ++r) {
                const float v = fast_tanh(acc[rt][ct][r] + (ct ? be2b : be2a));
                const int row = 16 * rt + 4 * l4 + r;
                const int col = c0 + ct * 16 + l15;
                const int idx = row * HH + (((col >> 3) ^ (row & 15)) * 8) + (col & 7);
                const unsigned short hv = f2bf(v);
                Ah[idx] = hv;
                Al[idx] = f2bf(v - bf2f(hv));
            }
    __syncthreads();                                          // B4

    // ---- stage 2: attn (bf16x3 GEMM + per-row reduce) ----
#pragma unroll
    for (int rt = 0; rt < 4; ++rt)
#pragma unroll
        for (int ct = 0; ct < 2; ++ct) acc[rt][ct] = (f32x4){0.f, 0.f, 0.f, 0.f};
    mfma_pass_dual(Ah, Al, Wa1h, acc, l15, l4, c0);
    mfma_pass_single(Ah, Wa1l, acc, l15, l4, c0);
#pragma unroll
    for (int rt = 0; rt < 4; ++rt)
#pragma unroll
        for (int r = 0; r < 4; ++r) {
            float s = fast_tanh(acc[rt][0][r] + ba1a) * wa2a +
                      fast_tanh(acc[rt][1][r] + ba1b) * wa2b;
            s += __shfl_xor(s, 1); s += __shfl_xor(s, 2);
            s += __shfl_xor(s, 4); s += __shfl_xor(s, 8);
            if (l15 == 0) part[wv * 64 + 16 * rt + 4 * l4 + r] = s;
        }
    __syncthreads();                                          // B5
    if (t < ETILE)
        attn_l[t] = fast_sigmoid(part[t] + part[64 + t] + part[128 + t] +
                                 part[192 + t] + ba2s);
    __syncthreads();                                          // B6

    // ---- stage 3: embed (single-bf16 GEMM; error attenuated by Wc2~1e-3) ----
#pragma unroll
    for (int rt = 0; rt < 4; ++rt)
#pragma unroll
        for (int ct = 0; ct < 2; ++ct) acc[rt][ct] = (f32x4){0.f, 0.f, 0.f, 0.f};
    mfma_pass_single(Ah, Wc1h, acc, l15, l4, c0);
#pragma unroll
    for (int rt = 0; rt < 4; ++rt)
#pragma unroll
        for (int r = 0; r < 4; ++r) {
            const int row = 16 * rt + 4 * l4 + r;
            const float at = attn_l[row];
            float s = fast_tanh(at * acc[rt][0][r] + bc1a) * wc2a +
                      fast_tanh(at * acc[rt][1][r] + bc1b) * wc2b;
            s += __shfl_xor(s, 1); s += __shfl_xor(s, 2);
            s += __shfl_xor(s, 4); s += __shfl_xor(s, 8);
            if (l15 == 0) part[wv * 64 + row] = s;
        }
    __syncthreads();                                          // B7
    if (t < ETILE)
        embed_l[t] = part[t] + part[64 + t] + part[128 + t] + part[192 + t];
    __syncthreads();                                          // B8

    // ---- epilogue: ef = m*attn (write) + agg (wave reduce) + cag ----
    {
        const float at = attn_l[e];
        float efv[32];
        float* orow = &ef_out[(((size_t)b * NN + i) * NN + (j0 + e)) * HH + c0];
#pragma unroll
        for (int s = 0; s < 4; ++s) {
            const int phys = (wv * 4 + s) ^ (e & 15);
            const u16x8 hv = *(const u16x8*)&Ah[e * HH + phys * 8];
            const u16x8 lv = *(const u16x8*)&Al[e * HH + phys * 8];
            f4 v0, v1;
            v0.x = (bf2f(hv[0]) + bf2f(lv[0])) * at;
            v0.y = (bf2f(hv[1]) + bf2f(lv[1])) * at;
            v0.z = (bf2f(hv[2]) + bf2f(lv[2])) * at;
            v0.w = (bf2f(hv[3]) + bf2f(lv[3])) * at;
            v1.x = (bf2f(hv[4]) + bf2f(lv[4])) * at;
            v1.y = (bf2f(hv[5]) + bf2f(lv[5])) * at;
            v1.z = (bf2f(hv[6]) + bf2f(lv[6])) * at;
            v1.w = (bf2f(hv[7]) + bf2f(lv[7])) * at;
            *(f4*)&orow[s * 8]     = v0;
            *(f4*)&orow[s * 8 + 4] = v1;
            efv[s * 8 + 0] = v0.x; efv[s * 8 + 1] = v0.y;
            efv[s * 8 + 2] = v0.z; efv[s * 8 + 3] = v0.w;
            efv[s * 8 + 4] = v1.x; efv[s * 8 + 5] = v1.y;
            efv[s * 8 + 6] = v1.z; efv[s * 8 + 7] = v1.w;
        }
        // agg over the wave's 64 edges (lane == e); waves own disjoint o-slices
#pragma unroll
        for (int q = 0; q < 32; ++q) {
            float v = efv[q];
            v += __shfl_xor(v, 1);  v += __shfl_xor(v, 2);
            v += __shfl_xor(v, 4);  v += __shfl_xor(v, 8);
            v += __shfl_xor(v, 16); v += __shfl_xor(v, 32);
            efv[q] = v;
        }
        if (e < 8) {
            f4 v; v.x = efv[e * 4]; v.y = efv[e * 4 + 1];
            v.z = efv[e * 4 + 2]; v.w = efv[e * 4 + 3];
            *(f4*)&agg_part[(size_t)bid * HH + c0 + e * 4] = v;
        }
    }
    if (t < ETILE) {
        const float em = embed_l[t];
        float tr0 = cd_l[t][0] * em, tr1 = cd_l[t][1] * em, tr2 = cd_l[t][2] * em;
#pragma unroll
        for (int off = 1; off < 64; off <<= 1) {
            tr0 += __shfl_xor(tr0, off);
            tr1 += __shfl_xor(tr1, off);
            tr2 += __shfl_xor(tr2, off);
        }
        if (t == 0) {
            cag_part[(size_t)bid * 3 + 0] = tr0;
            cag_part[(size_t)bid * 3 + 1] = tr1;
            cag_part[(size_t)bid * 3 + 2] = tr2;
        }
    }
}

// ---------------- Node kernel (fp32) ---------------------------------------
__global__ __launch_bounds__(128) void node_kernel(
    const float* __restrict__ h, const float* __restrict__ coord,
    const float* __restrict__ node_attr, const float* __restrict__ mask,
    const float* __restrict__ Wn1, const float* __restrict__ bn1,
    const float* __restrict__ Wn2, const float* __restrict__ bn2,
    const float* __restrict__ agg_part, const float* __restrict__ cag_part,
    float* __restrict__ h_out, float* __restrict__ c_out)
{
    const int bn = blockIdx.x;
    const int b  = bn / NN;
    const int t  = threadIdx.x;
    __shared__ float nl[2 * FF + HH];
    __shared__ float ul[HH];
    __shared__ float msp[2];
    const float mi = mask[bn];

    float s = mask[b * NN + t] + mask[b * NN + t + 128] + mask[b * NN + t + 256];
#pragma unroll
    for (int off = 1; off < 64; off <<= 1) s += __shfl_xor(s, off);
    if ((t & 63) == 0) msp[t >> 6] = s;

    if (t < FF) nl[t] = h[bn * FF + t] * mi;
    else        nl[t] = node_attr[bn * FF + (t - FF)] * mi;
    {
        float a = 0.f;
#pragma unroll
        for (int jc = 0; jc < NCHUNK; ++jc)
            a += agg_part[((size_t)bn * NCHUNK + jc) * HH + t];
        nl[2 * FF + t] = a * mi;
    }
    __syncthreads();

    float acc = bn1[t];
#pragma unroll 8
    for (int k = 0; k < 2 * FF + HH; ++k)
        acc = fmaf(nl[k], Wn1[k * HH + t], acc);
    ul[t] = fast_tanh(acc);
    __syncthreads();

    if (t < FF) {
        float a = bn2[t];
#pragma unroll 8
        for (int o = 0; o < HH; ++o)
            a = fmaf(ul[o], Wn2[o * FF + t], a);
        h_out[bn * FF + t] = (h[bn * FF + t] * mi + a) * mi;
    } else if (t < FF + 3) {
        const int d = t - FF;
        float cag = 0.f;
        for (int jc = 0; jc < NCHUNK; ++jc)
            cag += cag_part[((size_t)bn * NCHUNK + jc) * 3 + d];
        const float msum  = msp[0] + msp[1];
        const float denom = mi * msum + 1e-10f;
        c_out[bn * 3 + d] = (coord[bn * 3 + d] * mi + cag / denom) * mi;
    }
}

// ---------------- launch ----------------------------------------------------
extern "C" void kernel_launch(void* const* d_in, const int* in_sizes, int n_in,
                              void* d_out, int out_size, void* d_ws, size_t ws_size,
                              hipStream_t stream)
{
    const float* h         = (const float*)d_in[0];
    const float* coord     = (const float*)d_in[1];
    const float* edge_attr = (const float*)d_in[2];
    const float* node_attr = (const float*)d_in[3];
    const float* mask      = (const float*)d_in[4];
    const float* We1 = (const float*)d_in[5];
    const float* be1 = (const float*)d_in[6];
    const float* We2 = (const float*)d_in[7];
    const float* be2 = (const float*)d_in[8];
    const float* Wa1 = (const float*)d_in[9];
    const float* ba1 = (const float*)d_in[10];
    const float* Wa2 = (const float*)d_in[11];
    const float* ba2 = (const float*)d_in[12];
    const float* Wn1 = (const float*)d_in[13];
    const float* bn1 = (const float*)d_in[14];
    const float* Wn2 = (const float*)d_in[15];
    const float* bn2 = (const float*)d_in[16];
    const float* Wc1 = (const float*)d_in[17];
    const float* bc1 = (const float*)d_in[18];
    const float* Wc2 = (const float*)d_in[19];

    float* out    = (float*)d_out;
    float* h_out  = out;
    float* c_out  = out + (size_t)BB * NN * FF;
    float* ef_out = c_out + (size_t)BB * NN * 3;

    float* ws = (float*)d_ws;
    float* Sg = ws;                                             // B*N*128
    float* Tg = Sg + (size_t)BB * NN * HH;                      // B*N*128
    float* agg_part = Tg + (size_t)BB * NN * HH;                // B*N*6*128
    float* cag_part = agg_part + (size_t)BB * NN * NCHUNK * HH; // B*N*6*3
    unsigned short* WT = (unsigned short*)(cag_part + (size_t)BB * NN * NCHUNK * 3);
    // WT: 3 mats x {hi,lo} x 128x128 bf16 = 192 KB

    pre_kernel<<<BB * NN, 128, 0, stream>>>(h, mask, We1, be1, Sg, Tg);
    wconv_kernel<<<3 * HH, 128, 0, stream>>>(We2, Wa1, Wc1, WT);
    edge_kernel<<<BB * NN * NCHUNK, 256, 0, stream>>>(
        coord, edge_attr, mask, We1, be2, ba1, Wa2, ba2, bc1, Wc2,
        Sg, Tg, WT, ef_out, agg_part, cag_part);
    node_kernel<<<BB * NN, 128, 0, stream>>>(
        h, coord, node_attr, mask, Wn1, bn1, Wn2, bn2,
        agg_part, cag_part, h_out, c_out);
}

// Round 7
// 456.012 us; speedup vs baseline: 2.1259x; 1.0709x over previous
//
#include <hip/hip_runtime.h>

#define BB 2
#define NN 384
#define FF 64
#define HH 128
#define EE 4
#define ETILE 64
#define NCHUNK (NN / ETILE)   // 6
#define PRE_NB 16
#define NODE_NB 8

using f4 = float4;
typedef __attribute__((ext_vector_type(8))) short          bf16x8;
typedef __attribute__((ext_vector_type(8))) unsigned short u16x8;
typedef __attribute__((ext_vector_type(4))) unsigned short u16x4;
typedef __attribute__((ext_vector_type(4))) unsigned int   u32x4;
typedef __attribute__((ext_vector_type(4))) float          f32x4;

__device__ __forceinline__ float fast_tanh(float x) {
    float e = __expf(2.0f * x);
    return 1.0f - 2.0f / (e + 1.0f);
}
__device__ __forceinline__ float fast_sigmoid(float x) {
    return 1.0f / (1.0f + __expf(-x));
}
__device__ __forceinline__ unsigned short f2bf(float x) {   // RNE
    unsigned int u = __float_as_uint(x);
    unsigned int r = (u + 0x7fffu + ((u >> 16) & 1u)) >> 16;
    return (unsigned short)r;
}
__device__ __forceinline__ float bf2f(unsigned short h) {
    return __uint_as_float(((unsigned int)h) << 16);
}
__device__ __forceinline__ bf16x8 as_bf16x8(u32x4 v) {
    union { u32x4 u; bf16x8 b; } c; c.u = v; return c.b;
}

// ---------------- Kernel A: S/T precompute (16 nodes/block) ----------------
// weight traffic amortized: 48 blocks x 64KB = 3MB (was 49MB)
__global__ __launch_bounds__(128) void pre_kernel(
    const float* __restrict__ h, const float* __restrict__ mask,
    const float* __restrict__ We1, const float* __restrict__ be1,
    float* __restrict__ Sg, float* __restrict__ Tg)
{
    const int n0 = blockIdx.x * PRE_NB;
    const int t  = threadIdx.x;       // output col 0..127
    __shared__ float hl[PRE_NB][FF];
    for (int q = t; q < PRE_NB * FF; q += 128) {
        const int n = q >> 6, f = q & 63;
        hl[n][f] = h[(n0 + n) * FF + f] * mask[n0 + n];
    }
    __syncthreads();
    float accS[PRE_NB], accT[PRE_NB];
    const float b1 = be1[t];
#pragma unroll
    for (int n = 0; n < PRE_NB; ++n) { accS[n] = 0.f; accT[n] = b1; }
    for (int f = 0; f < FF; ++f) {
        const float ws = We1[f * HH + t];
        const float wt = We1[(FF + f) * HH + t];
#pragma unroll
        for (int n = 0; n < PRE_NB; ++n) {
            accS[n] = fmaf(hl[n][f], ws, accS[n]);
            accT[n] = fmaf(hl[n][f], wt, accT[n]);
        }
    }
#pragma unroll
    for (int n = 0; n < PRE_NB; ++n) {
        Sg[(n0 + n) * HH + t] = accS[n];
        Tg[(n0 + n) * HH + t] = accT[n];
    }
}

// ---------------- Kernel B: weight transpose + bf16 hi/lo split ------------
__global__ __launch_bounds__(128) void wconv_kernel(
    const float* __restrict__ W0, const float* __restrict__ W1,
    const float* __restrict__ W2, unsigned short* __restrict__ WT)
{
    const int mat = blockIdx.x >> 7;
    const int o   = blockIdx.x & 127;
    const int k   = threadIdx.x;
    const float* src = (mat == 0) ? W0 : (mat == 1) ? W1 : W2;
    const float w = src[k * HH + o];
    const unsigned short hi = f2bf(w);
    const unsigned short lo = f2bf(w - bf2f(hi));
    WT[(mat * 2 + 0) * 16384 + o * HH + k] = hi;
    WT[(mat * 2 + 1) * 16384 + o * HH + k] = lo;
}

// ---------------- MFMA pass helpers (PROVEN — unchanged) -------------------
__device__ __forceinline__ void mfma_pass_dual(
    const ushort* __restrict__ A1, const ushort* __restrict__ A2,
    const ushort* __restrict__ WTp, f32x4 acc[4][2],
    const int l15, const int l4, const int c0)
{
    u32x4 Bf[2][4];
#pragma unroll
    for (int ct = 0; ct < 2; ++ct)
#pragma unroll
        for (int kb = 0; kb < 4; ++kb)
            Bf[ct][kb] = *(const u32x4*)&WTp[(c0 + ct * 16 + l15) * HH + kb * 32 + l4 * 8];
#pragma unroll
    for (int rt = 0; rt < 4; ++rt) {
        bf16x8 Af1[4], Af2[4];
#pragma unroll
        for (int kb = 0; kb < 4; ++kb) {
            const int idx = (16 * rt + l15) * HH + (((kb * 4 + l4) ^ l15) * 8);
            Af1[kb] = *(const bf16x8*)&A1[idx];
            Af2[kb] = *(const bf16x8*)&A2[idx];
        }
#pragma unroll
        for (int ct = 0; ct < 2; ++ct)
#pragma unroll
            for (int kb = 0; kb < 4; ++kb)
                acc[rt][ct] = __builtin_amdgcn_mfma_f32_16x16x32_bf16(
                    Af1[kb], as_bf16x8(Bf[ct][kb]), acc[rt][ct], 0, 0, 0);
#pragma unroll
        for (int ct = 0; ct < 2; ++ct)
#pragma unroll
            for (int kb = 0; kb < 4; ++kb)
                acc[rt][ct] = __builtin_amdgcn_mfma_f32_16x16x32_bf16(
                    Af2[kb], as_bf16x8(Bf[ct][kb]), acc[rt][ct], 0, 0, 0);
    }
}

__device__ __forceinline__ void mfma_pass_single(
    const ushort* __restrict__ A1, const ushort* __restrict__ WTp,
    f32x4 acc[4][2], const int l15, const int l4, const int c0)
{
    u32x4 Bf[2][4];
#pragma unroll
    for (int ct = 0; ct < 2; ++ct)
#pragma unroll
        for (int kb = 0; kb < 4; ++kb)
            Bf[ct][kb] = *(const u32x4*)&WTp[(c0 + ct * 16 + l15) * HH + kb * 32 + l4 * 8];
#pragma unroll
    for (int rt = 0; rt < 4; ++rt) {
        bf16x8 Af1[4];
#pragma unroll
        for (int kb = 0; kb < 4; ++kb) {
            const int idx = (16 * rt + l15) * HH + (((kb * 4 + l4) ^ l15) * 8);
            Af1[kb] = *(const bf16x8*)&A1[idx];
        }
#pragma unroll
        for (int ct = 0; ct < 2; ++ct)
#pragma unroll
            for (int kb = 0; kb < 4; ++kb)
                acc[rt][ct] = __builtin_amdgcn_mfma_f32_16x16x32_bf16(
                    Af1[kb], as_bf16x8(Bf[ct][kb]), acc[rt][ct], 0, 0, 0);
    }
}

// ---------------- Edge kernel (MFMA bf16x3, coalesced epilogue) ------------
__global__ __launch_bounds__(256, 4) void edge_kernel(
    const float* __restrict__ coord, const float* __restrict__ edge_attr,
    const float* __restrict__ mask,  const float* __restrict__ We1,
    const float* __restrict__ be2,   const float* __restrict__ ba1,
    const float* __restrict__ Wa2,   const float* __restrict__ ba2,
    const float* __restrict__ bc1,   const float* __restrict__ Wc2,
    const float* __restrict__ Sg,    const float* __restrict__ Tg,
    const unsigned short* __restrict__ WT,
    float* __restrict__ ef_out,
    float* __restrict__ agg_part,    // [B*N*NCHUNK][128]
    float* __restrict__ cag_part)    // [B*N*NCHUNK][3]
{
    __shared__ ushort Ah[ETILE * HH];   // 16 KB, swizzled bf16 hi
    __shared__ ushort Al[ETILE * HH];   // 16 KB, swizzled bf16 lo
    __shared__ float Tb[HH];
    __shared__ float sd_l[ETILE];
    __shared__ float cd_l[ETILE][3];
    __shared__ float ea_l[ETILE][4];
    __shared__ float attn_l[ETILE];
    __shared__ float embed_l[ETILE];
    __shared__ float part[512];

    const int bid = blockIdx.x;
    const int jc  = bid % NCHUNK;
    const int i   = (bid / NCHUNK) % NN;
    const int b   = bid / (NCHUNK * NN);
    const int j0  = jc * ETILE;
    const int t   = threadIdx.x;
    const int e   = t & 63;                                   // lane id too
    const int wv  = __builtin_amdgcn_readfirstlane(t >> 6);   // wave id
    const int l15 = e & 15, l4 = e >> 4;
    const int c0  = wv * 32;                                  // wave col base

    const unsigned short* We2h = WT;
    const unsigned short* We2l = WT + 16384;
    const unsigned short* Wa1h = WT + 32768;
    const unsigned short* Wa1l = WT + 49152;
    const unsigned short* Wc1h = WT + 65536;

    const float be2a = be2[c0 + l15],      be2b = be2[c0 + 16 + l15];
    const float ba1a = ba1[c0 + l15],      ba1b = ba1[c0 + 16 + l15];
    const float wa2a = Wa2[c0 + l15],      wa2b = Wa2[c0 + 16 + l15];
    const float bc1a = bc1[c0 + l15],      bc1b = bc1[c0 + 16 + l15];
    const float wc2a = Wc2[c0 + l15],      wc2b = Wc2[c0 + 16 + l15];
    const float ba2s = ba2[0];

    if (t < HH) Tb[t] = Tg[(b * NN + i) * HH + t];
    if (t < ETILE) {
        const int j = j0 + t;
        const float mi = mask[b * NN + i], mj = mask[b * NN + j];
        const float m2 = mi * mj;
        const float d0 = coord[(b * NN + i) * 3 + 0] * mi - coord[(b * NN + j) * 3 + 0] * mj;
        const float d1 = coord[(b * NN + i) * 3 + 1] * mi - coord[(b * NN + j) * 3 + 1] * mj;
        const float d2 = coord[(b * NN + i) * 3 + 2] * mi - coord[(b * NN + j) * 3 + 2] * mj;
        sd_l[t] = (d0 * d0 + d1 * d1 + d2 * d2) * m2;
        cd_l[t][0] = d0 * m2; cd_l[t][1] = d1 * m2; cd_l[t][2] = d2 * m2;
        const f4 ea = *(const f4*)&edge_attr[(((size_t)b * NN + i) * NN + j) * EE];
        ea_l[t][0] = ea.x; ea_l[t][1] = ea.y; ea_l[t][2] = ea.z; ea_l[t][3] = ea.w;
    }
    __syncthreads();                                          // B1

    // ---- phase 0: m1 = tanh(S[j] + T[i] + rad*W1r + ea@W1e) -> Ah/Al ----
    {
        const float rad = sd_l[e];
        const float ea0 = ea_l[e][0], ea1 = ea_l[e][1], ea2 = ea_l[e][2], ea3 = ea_l[e][3];
        const float* Srow = &Sg[((size_t)b * NN + (j0 + e)) * HH];
#pragma unroll
        for (int s = 0; s < 4; ++s) {
            u16x8 hp, lp;
#pragma unroll
            for (int hq = 0; hq < 2; ++hq) {
                const int o = c0 + s * 8 + hq * 4;
                const f4 sv = *(const f4*)&Srow[o];
                const f4 tb = *(const f4*)&Tb[o];
                const f4 wr = *(const f4*)&We1[128 * HH + o];
                const f4 w0 = *(const f4*)&We1[129 * HH + o];
                const f4 w1 = *(const f4*)&We1[130 * HH + o];
                const f4 w2 = *(const f4*)&We1[131 * HH + o];
                const f4 w3 = *(const f4*)&We1[132 * HH + o];
                float pv[4];
                pv[0] = sv.x + tb.x + rad * wr.x + ea0 * w0.x + ea1 * w1.x + ea2 * w2.x + ea3 * w3.x;
                pv[1] = sv.y + tb.y + rad * wr.y + ea0 * w0.y + ea1 * w1.y + ea2 * w2.y + ea3 * w3.y;
                pv[2] = sv.z + tb.z + rad * wr.z + ea0 * w0.z + ea1 * w1.z + ea2 * w2.z + ea3 * w3.z;
                pv[3] = sv.w + tb.w + rad * wr.w + ea0 * w0.w + ea1 * w1.w + ea2 * w2.w + ea3 * w3.w;
#pragma unroll
                for (int q = 0; q < 4; ++q) {
                    const float v = fast_tanh(pv[q]);
                    const unsigned short hv = f2bf(v);
                    hp[hq * 4 + q] = hv;
                    lp[hq * 4 + q] = f2bf(v - bf2f(hv));
                }
            }
            const int phys = (wv * 4 + s) ^ (e & 15);
            *(u16x8*)&Ah[e * HH + phys * 8] = hp;
            *(u16x8*)&Al[e * HH + phys * 8] = lp;
        }
    }
    __syncthreads();                                          // B2

    f32x4 acc[4][2];

    // ---- stage 1: m = tanh(m1 @ We2 + be2) (bf16x3), in place ----
#pragma unroll
    for (int rt = 0; rt < 4; ++rt)
#pragma unroll
        for (int ct = 0; ct < 2; ++ct) acc[rt][ct] = (f32x4){0.f, 0.f, 0.f, 0.f};
    mfma_pass_dual(Ah, Al, We2h, acc, l15, l4, c0);
    mfma_pass_single(Ah, We2l, acc, l15, l4, c0);
    __syncthreads();                                          // B3
#pragma unroll
    for (int rt = 0; rt < 4; ++rt)
#pragma unroll
        for (int ct = 0; ct < 2; ++ct)
#pragma unroll
            for (int r = 0; r < 4; ++r) {
                const float v = fast_tanh(acc[rt][ct][r] + (ct ? be2b : be2a));
                const int row = 16 * rt + 4 * l4 + r;
                const int col = c0 + ct * 16 + l15;
                const int idx = row * HH + (((col >> 3) ^ (row & 15)) * 8) + (col & 7);
                const unsigned short hv = f2bf(v);
                Ah[idx] = hv;
                Al[idx] = f2bf(v - bf2f(hv));
            }
    __syncthreads();                                          // B4

    // ---- stage 2: attn (bf16x3 GEMM + per-row reduce) ----
#pragma unroll
    for (int rt = 0; rt < 4; ++rt)
#pragma unroll
        for (int ct = 0; ct < 2; ++ct) acc[rt][ct] = (f32x4){0.f, 0.f, 0.f, 0.f};
    mfma_pass_dual(Ah, Al, Wa1h, acc, l15, l4, c0);
    mfma_pass_single(Ah, Wa1l, acc, l15, l4, c0);
#pragma unroll
    for (int rt = 0; rt < 4; ++rt)
#pragma unroll
        for (int r = 0; r < 4; ++r) {
            float s = fast_tanh(acc[rt][0][r] + ba1a) * wa2a +
                      fast_tanh(acc[rt][1][r] + ba1b) * wa2b;
            s += __shfl_xor(s, 1); s += __shfl_xor(s, 2);
            s += __shfl_xor(s, 4); s += __shfl_xor(s, 8);
            if (l15 == 0) part[wv * 64 + 16 * rt + 4 * l4 + r] = s;
        }
    __syncthreads();                                          // B5
    if (t < ETILE)
        attn_l[t] = fast_sigmoid(part[t] + part[64 + t] + part[128 + t] +
                                 part[192 + t] + ba2s);
    __syncthreads();                                          // B6

    // ---- stage 3: embed (single-bf16 GEMM) ----
#pragma unroll
    for (int rt = 0; rt < 4; ++rt)
#pragma unroll
        for (int ct = 0; ct < 2; ++ct) acc[rt][ct] = (f32x4){0.f, 0.f, 0.f, 0.f};
    mfma_pass_single(Ah, Wc1h, acc, l15, l4, c0);
#pragma unroll
    for (int rt = 0; rt < 4; ++rt)
#pragma unroll
        for (int r = 0; r < 4; ++r) {
            const int row = 16 * rt + 4 * l4 + r;
            const float at = attn_l[row];
            float s = fast_tanh(at * acc[rt][0][r] + bc1a) * wc2a +
                      fast_tanh(at * acc[rt][1][r] + bc1b) * wc2b;
            s += __shfl_xor(s, 1); s += __shfl_xor(s, 2);
            s += __shfl_xor(s, 4); s += __shfl_xor(s, 8);
            if (l15 == 0) part[wv * 64 + row] = s;
        }
    __syncthreads();                                          // B7
    if (t < ETILE)
        embed_l[t] = part[t] + part[64 + t] + part[128 + t] + part[192 + t];
    __syncthreads();                                          // B8

    // ---- epilogue: COALESCED ef writes (full-line) + cheap agg ----
    // thread t -> (erow = t>>5, colq = t&31); 8 iterations over row-groups.
    // per store-inst: 64 lanes x 16B contiguous (2 full rows = 1KB) -> no RFO.
    {
        const int erow = t >> 5;
        const int colq = t & 31;
        const int col  = colq * 4;
        const int chunk = col >> 3;
        const int sub   = col & 7;
        float a0 = 0.f, a1 = 0.f, a2 = 0.f, a3 = 0.f;
        float* obase = &ef_out[(((size_t)b * NN + i) * NN + j0) * HH];
#pragma unroll
        for (int it = 0; it < 8; ++it) {
            const int row = it * 8 + erow;
            const float at = attn_l[row];
            const int idx = row * HH + ((chunk ^ (row & 15)) * 8) + sub;
            const u16x4 hv4 = *(const u16x4*)&Ah[idx];
            const u16x4 lv4 = *(const u16x4*)&Al[idx];
            f4 v;
            v.x = (bf2f(hv4[0]) + bf2f(lv4[0])) * at;
            v.y = (bf2f(hv4[1]) + bf2f(lv4[1])) * at;
            v.z = (bf2f(hv4[2]) + bf2f(lv4[2])) * at;
            v.w = (bf2f(hv4[3]) + bf2f(lv4[3])) * at;
            *(f4*)&obase[row * HH + col] = v;
            a0 += v.x; a1 += v.y; a2 += v.z; a3 += v.w;
        }
        a0 += __shfl_xor(a0, 32);
        a1 += __shfl_xor(a1, 32);
        a2 += __shfl_xor(a2, 32);
        a3 += __shfl_xor(a3, 32);
        if (e < 32) {
            part[wv * HH + col + 0] = a0;
            part[wv * HH + col + 1] = a1;
            part[wv * HH + col + 2] = a2;
            part[wv * HH + col + 3] = a3;
        }
    }
    // coord aggregation (wave 0)
    if (t < ETILE) {
        const float em = embed_l[t];
        float tr0 = cd_l[t][0] * em, tr1 = cd_l[t][1] * em, tr2 = cd_l[t][2] * em;
#pragma unroll
        for (int off = 1; off < 64; off <<= 1) {
            tr0 += __shfl_xor(tr0, off);
            tr1 += __shfl_xor(tr1, off);
            tr2 += __shfl_xor(tr2, off);
        }
        if (t == 0) {
            cag_part[(size_t)bid * 3 + 0] = tr0;
            cag_part[(size_t)bid * 3 + 1] = tr1;
            cag_part[(size_t)bid * 3 + 2] = tr2;
        }
    }
    __syncthreads();                                          // B9
    if (t < HH)
        agg_part[(size_t)bid * HH + t] =
            part[t] + part[HH + t] + part[2 * HH + t] + part[3 * HH + t];
}

// ---------------- Node kernel (8 nodes/block, amortized weights) -----------
__global__ __launch_bounds__(256) void node_kernel(
    const float* __restrict__ h, const float* __restrict__ coord,
    const float* __restrict__ node_attr, const float* __restrict__ mask,
    const float* __restrict__ Wn1, const float* __restrict__ bn1,
    const float* __restrict__ Wn2, const float* __restrict__ bn2,
    const float* __restrict__ agg_part, const float* __restrict__ cag_part,
    float* __restrict__ h_out, float* __restrict__ c_out)
{
    const int n0 = blockIdx.x * NODE_NB;      // 96 blocks; b uniform per block
    const int b  = n0 / NN;
    const int t  = threadIdx.x;
    __shared__ float nl[NODE_NB][2 * FF + HH];   // 8 KB
    __shared__ float ul[NODE_NB][HH];            // 4 KB
    __shared__ float pp[4][NODE_NB][HH];         // 16 KB
    __shared__ float msum_s;

    for (int q = t; q < NODE_NB * 256; q += 256) {
        const int n = q >> 8, k = q & 255;
        const int bn = n0 + n;
        const float mi = mask[bn];
        float v;
        if (k < FF)          v = h[bn * FF + k] * mi;
        else if (k < 2 * FF) v = node_attr[bn * FF + (k - FF)] * mi;
        else {
            float a = 0.f;
            const int o = k - 2 * FF;
#pragma unroll
            for (int jc = 0; jc < NCHUNK; ++jc)
                a += agg_part[((size_t)bn * NCHUNK + jc) * HH + o];
            v = a * mi;
        }
        nl[n][k] = v;
    }
    if (t < 64) {
        float s = 0.f;
#pragma unroll
        for (int q = 0; q < 6; ++q) s += mask[b * NN + q * 64 + t];
#pragma unroll
        for (int off = 1; off < 64; off <<= 1) s += __shfl_xor(s, off);
        if (t == 0) msum_s = s;
    }
    __syncthreads();

    // layer 1: k split in halves across threads
    {
        const int col = t & 127, kh = t >> 7;
        float acc[NODE_NB];
#pragma unroll
        for (int n = 0; n < NODE_NB; ++n) acc[n] = 0.f;
        for (int k = kh * 128; k < kh * 128 + 128; ++k) {
            const float w = Wn1[k * HH + col];
#pragma unroll
            for (int n = 0; n < NODE_NB; ++n)
                acc[n] = fmaf(nl[n][k], w, acc[n]);
        }
#pragma unroll
        for (int n = 0; n < NODE_NB; ++n) pp[kh][n][col] = acc[n];
    }
    __syncthreads();
#pragma unroll
    for (int r = 0; r < 4; ++r) {
        const int idx = t + 256 * r;
        const int n = idx >> 7, col = idx & 127;
        ul[n][col] = fast_tanh(pp[0][n][col] + pp[1][n][col] + bn1[col]);
    }
    __syncthreads();

    // layer 2: k split in quarters
    {
        const int col = t & 63, ks = t >> 6;
        float acc[NODE_NB];
#pragma unroll
        for (int n = 0; n < NODE_NB; ++n) acc[n] = 0.f;
        for (int k = ks * 32; k < ks * 32 + 32; ++k) {
            const float w = Wn2[k * FF + col];
#pragma unroll
            for (int n = 0; n < NODE_NB; ++n)
                acc[n] = fmaf(ul[n][k], w, acc[n]);
        }
#pragma unroll
        for (int n = 0; n < NODE_NB; ++n) pp[ks][n][col] = acc[n];
    }
    __syncthreads();
#pragma unroll
    for (int r = 0; r < 2; ++r) {
        const int idx = t + 256 * r;
        const int n = idx >> 6, col = idx & 63;
        const int bn = n0 + n;
        const float mi = mask[bn];
        const float a = pp[0][n][col] + pp[1][n][col] + pp[2][n][col] +
                        pp[3][n][col] + bn2[col];
        h_out[bn * FF + col] = (nl[n][col] + a) * mi;   // nl[n][col] = h*mi
    }
    if (t < NODE_NB * 3) {
        const int n = t / 3, d = t % 3;
        const int bn = n0 + n;
        const float mi = mask[bn];
        float cag = 0.f;
#pragma unroll
        for (int jc = 0; jc < NCHUNK; ++jc)
            cag += cag_part[((size_t)bn * NCHUNK + jc) * 3 + d];
        const float denom = mi * msum_s + 1e-10f;
        c_out[bn * 3 + d] = (coord[bn * 3 + d] * mi + cag / denom) * mi;
    }
}

// ---------------- launch ----------------------------------------------------
extern "C" void kernel_launch(void* const* d_in, const int* in_sizes, int n_in,
                              void* d_out, int out_size, void* d_ws, size_t ws_size,
                              hipStream_t stream)
{
    const float* h         = (const float*)d_in[0];
    const float* coord     = (const float*)d_in[1];
    const float* edge_attr = (const float*)d_in[2];
    const float* node_attr = (const float*)d_in[3];
    const float* mask      = (const float*)d_in[4];
    const float* We1 = (const float*)d_in[5];
    const float* be1 = (const float*)d_in[6];
    const float* We2 = (const float*)d_in[7];
    const float* be2 = (const float*)d_in[8];
    const float* Wa1 = (const float*)d_in[9];
    const float* ba1 = (const float*)d_in[10];
    const float* Wa2 = (const float*)d_in[11];
    const float* ba2 = (const float*)d_in[12];
    const float* Wn1 = (const float*)d_in[13];
    const float* bn1 = (const float*)d_in[14];
    const float* Wn2 = (const float*)d_in[15];
    const float* bn2 = (const float*)d_in[16];
    const float* Wc1 = (const float*)d_in[17];
    const float* bc1 = (const float*)d_in[18];
    const float* Wc2 = (const float*)d_in[19];

    float* out    = (float*)d_out;
    float* h_out  = out;
    float* c_out  = out + (size_t)BB * NN * FF;
    float* ef_out = c_out + (size_t)BB * NN * 3;

    float* ws = (float*)d_ws;
    float* Sg = ws;                                             // B*N*128
    float* Tg = Sg + (size_t)BB * NN * HH;                      // B*N*128
    float* agg_part = Tg + (size_t)BB * NN * HH;                // B*N*6*128
    float* cag_part = agg_part + (size_t)BB * NN * NCHUNK * HH; // B*N*6*3
    unsigned short* WT = (unsigned short*)(cag_part + (size_t)BB * NN * NCHUNK * 3);
    // WT: 3 mats x {hi,lo} x 128x128 bf16 = 192 KB

    pre_kernel<<<BB * NN / PRE_NB, 128, 0, stream>>>(h, mask, We1, be1, Sg, Tg);
    wconv_kernel<<<3 * HH, 128, 0, stream>>>(We2, Wa1, Wc1, WT);
    edge_kernel<<<BB * NN * NCHUNK, 256, 0, stream>>>(
        coord, edge_attr, mask, We1, be2, ba1, Wa2, ba2, bc1, Wc2,
        Sg, Tg, WT, ef_out, agg_part, cag_part);
    node_kernel<<<BB * NN / NODE_NB, 256, 0, stream>>>(
        h, coord, node_attr, mask, Wn1, bn1, Wn2, bn2,
        agg_part, cag_part, h_out, c_out);
}